// Round 1
// baseline (589.090 us; speedup 1.0000x reference)
//
#include <hip/hip_runtime.h>
#include <hip/hip_bf16.h>
#include <hip/hip_fp16.h>

#define NS   100000
#define CIN  96
#define CHID 576
#define COUT 96

typedef float    floatx4 __attribute__((ext_vector_type(4)));
typedef short    short8  __attribute__((ext_vector_type(8)));
typedef _Float16 half8   __attribute__((ext_vector_type(8)));

// ---------------------------------------------------------------------------
// K0: transpose+convert weights.  w1 [96][576] f32 -> w1T [576][96] bf16 bits.
//     w3 [576][96] f32 -> w3T [96][576] fp16.  Values are ints <=127 -> exact.
// ---------------------------------------------------------------------------
__global__ void prep_kernel(const float* __restrict__ w1, const float* __restrict__ w3,
                            unsigned short* __restrict__ w1T, _Float16* __restrict__ w3T) {
  int i = blockIdx.x * blockDim.x + threadIdx.x;
  if (i >= CHID * CIN) return;
  {
    int h = i / CIN, k = i % CIN;  // w1T[h][k] = w1[k][h]
    // truncation to bf16 is exact for small integers
    w1T[i] = (unsigned short)(__float_as_uint(w1[k * CHID + h]) >> 16);
  }
  {
    int o = i / CHID, k = i % CHID;  // w3T[o][k] = w3[k][o]
    w3T[i] = (_Float16)w3[k * COUT + o];
  }
}

// ---------------------------------------------------------------------------
// K1: expand GEMM  x1 = relu6(clamp(requant(feats@w1 + b1, s1)))  -> fp16 exact
// One wave per 16 sites; loops over 36 h-tiles of 16.  K=96 -> 3 MFMAs/tile.
// A-frag: A[m=lane&15][k=quad*8+j]; B-frag: B[k=quad*8+j][n=lane&15];
// C/D: col=lane&15 (h), row=quad*4+reg (site).
// ---------------------------------------------------------------------------
__global__ __launch_bounds__(64) void expand_kernel(
    const float* __restrict__ feats, const float* __restrict__ b1,
    const float* __restrict__ s1, const unsigned short* __restrict__ w1T,
    _Float16* __restrict__ x1h) {
  const int lane = threadIdx.x;
  const int m = lane & 15, quad = lane >> 4;
  const int s0 = blockIdx.x * 16;

  // Load + convert the A fragments (all of K=96) once.
  short8 afrag[3];
  const float* arow = feats + (s0 + m) * CIN + quad * 8;
#pragma unroll
  for (int kc = 0; kc < 3; ++kc) {
    const float4 lo = *reinterpret_cast<const float4*>(arow + kc * 32);
    const float4 hi = *reinterpret_cast<const float4*>(arow + kc * 32 + 4);
    const float v[8] = {lo.x, lo.y, lo.z, lo.w, hi.x, hi.y, hi.z, hi.w};
#pragma unroll
    for (int j = 0; j < 8; ++j)
      afrag[kc][j] = (short)(__float_as_uint(v[j]) >> 16);  // exact: ints <=127
  }

  for (int ht = 0; ht < CHID / 16; ++ht) {
    const int h = ht * 16 + m;
    floatx4 acc = {0.f, 0.f, 0.f, 0.f};
#pragma unroll
    for (int kc = 0; kc < 3; ++kc) {
      const short8 bfrag =
          *reinterpret_cast<const short8*>(w1T + h * CIN + kc * 32 + quad * 8);
      acc = __builtin_amdgcn_mfma_f32_16x16x32_bf16(afrag[kc], bfrag, acc, 0, 0, 0);
    }
    const float scale = rintf(s1[h]) * (1.0f / 256.0f);  // round(s)*B/(B*B)
    const float bias = b1[h];
#pragma unroll
    for (int r = 0; r < 4; ++r) {
      const int site = s0 + quad * 4 + r;
      float v = (acc[r] + bias) * scale;
      v = fminf(fmaxf(v, 0.0f), 6.0f);  // clamp(-128,128) then relu6 == clip(0,6)
      x1h[site * CHID + h] = (_Float16)v;
    }
  }
}

// ---------------------------------------------------------------------------
// K2: sparse depthwise 3x3.  x2 = relu6(clamp(requant(sum_k x1[nbr]*w2 + b2)))
// Block = 576 threads (one channel each); loop over sites; uniform-branch
// skip of invalid taps (~60% of gathers skipped on average).
// ---------------------------------------------------------------------------
__global__ __launch_bounds__(576) void dw_kernel(
    const int* __restrict__ nbr, const float* __restrict__ w2,
    const float* __restrict__ b2, const float* __restrict__ s2,
    const _Float16* __restrict__ x1h, _Float16* __restrict__ x2h,
    int sites_per_block) {
  const int c = threadIdx.x;
  float w[9];
#pragma unroll
  for (int k = 0; k < 9; ++k) w[k] = w2[k * CHID + c];
  const float bias = b2[c];
  const float scale = rintf(s2[c]) * (1.0f / 256.0f);
  const int start = blockIdx.x * sites_per_block;
  const int end = min(start + sites_per_block, NS);
  for (int n = start; n < end; ++n) {
    float acc = bias;
#pragma unroll
    for (int k = 0; k < 9; ++k) {
      const int idx = nbr[k * NS + n];  // block-uniform
      if (idx >= 0) acc += (float)x1h[idx * CHID + c] * w[k];
    }
    float v = acc * scale;
    v = fminf(fmaxf(v, 0.0f), 6.0f);
    x2h[n * CHID + c] = (_Float16)v;
  }
}

// ---------------------------------------------------------------------------
// K3: project GEMM + residual.
// x3 = clamp(requant(x2@w3 + b3, s3)); out = round(s_main)*256*x3
//                                          + round(s_res)*256*feats
// One wave per 16 sites; holds all K=576 A-fragments in regs (72 VGPRs).
// ---------------------------------------------------------------------------
__global__ __launch_bounds__(64) void proj_kernel(
    const _Float16* __restrict__ x2h, const float* __restrict__ feats,
    const float* __restrict__ b3, const float* __restrict__ s3,
    const _Float16* __restrict__ w3T, const float* __restrict__ s_main,
    const float* __restrict__ s_res, float* __restrict__ out) {
  const int lane = threadIdx.x;
  const int m = lane & 15, quad = lane >> 4;
  const int s0 = blockIdx.x * 16;

  half8 afrag[18];
  const _Float16* arow = x2h + (s0 + m) * CHID + quad * 8;
#pragma unroll
  for (int kc = 0; kc < 18; ++kc)
    afrag[kc] = *reinterpret_cast<const half8*>(arow + kc * 32);

  const float rsm = rintf(s_main[0]) * 256.0f;
  const float rsr = rintf(s_res[0]) * 256.0f;

  for (int ot = 0; ot < COUT / 16; ++ot) {
    const int o = ot * 16 + m;
    floatx4 acc = {0.f, 0.f, 0.f, 0.f};
    const _Float16* brow = w3T + o * CHID + quad * 8;
#pragma unroll
    for (int kc = 0; kc < 18; ++kc) {
      const half8 bfrag = *reinterpret_cast<const half8*>(brow + kc * 32);
      acc = __builtin_amdgcn_mfma_f32_16x16x32_f16(afrag[kc], bfrag, acc, 0, 0, 0);
    }
    const float scale = rintf(s3[o]) * (1.0f / 256.0f);
    const float bias = b3[o];
#pragma unroll
    for (int r = 0; r < 4; ++r) {
      const int site = s0 + quad * 4 + r;
      float v = (acc[r] + bias) * scale;
      v = fminf(fmaxf(v, -128.0f), 128.0f);  // clamp only, no relu6
      out[site * COUT + o] = rsm * v + rsr * feats[site * COUT + o];
    }
  }
}

// ---------------------------------------------------------------------------
extern "C" void kernel_launch(void* const* d_in, const int* in_sizes, int n_in,
                              void* d_out, int out_size, void* d_ws, size_t ws_size,
                              hipStream_t stream) {
  const float* feats  = (const float*)d_in[0];
  const int*   nbr    = (const int*)d_in[1];
  const float* w1     = (const float*)d_in[2];
  const float* b1     = (const float*)d_in[3];
  const float* w2     = (const float*)d_in[4];
  const float* b2     = (const float*)d_in[5];
  const float* w3     = (const float*)d_in[6];
  const float* b3     = (const float*)d_in[7];
  const float* s1     = (const float*)d_in[8];
  const float* s2     = (const float*)d_in[9];
  const float* s3     = (const float*)d_in[10];
  const float* s_main = (const float*)d_in[11];
  const float* s_res  = (const float*)d_in[12];
  float* out = (float*)d_out;

  char* ws = (char*)d_ws;
  _Float16*       x1h = (_Float16*)ws;                       // 115,200,000 B
  _Float16*       x2h = (_Float16*)(ws + 115200000);         // 115,200,000 B
  unsigned short* w1T = (unsigned short*)(ws + 230400000);   // 110,592 B
  _Float16*       w3T = (_Float16*)(ws + 230510592);         // 110,592 B

  prep_kernel<<<(CHID * CIN + 255) / 256, 256, 0, stream>>>(w1, w3, w1T, w3T);
  expand_kernel<<<NS / 16, 64, 0, stream>>>(feats, b1, s1, w1T, x1h);
  const int spb = 100;
  dw_kernel<<<(NS + spb - 1) / spb, CHID, 0, stream>>>(nbr, w2, b2, s2, x1h, x2h, spb);
  proj_kernel<<<NS / 16, 64, 0, stream>>>(x2h, feats, b3, s3, w3T, s_main, s_res, out);
}

// Round 2
// 402.977 us; speedup vs baseline: 1.4618x; 1.4618x over previous
//
#include <hip/hip_runtime.h>
#include <hip/hip_bf16.h>
#include <hip/hip_fp16.h>

#define NS   100000
#define CIN  96
#define CHID 576
#define COUT 96
#define SPB  48              // sites per block in fused dw+proj
#define LDH  (CHID + 8)      // padded LDS row (halves): +16B breaks bank conflicts

typedef float    floatx4 __attribute__((ext_vector_type(4)));
typedef short    short8  __attribute__((ext_vector_type(8)));
typedef _Float16 half8   __attribute__((ext_vector_type(8)));

// ---------------------------------------------------------------------------
// K0: transpose+convert weights; also zero the dummy gather row x1h[NS].
// w1 [96][576] f32 -> w1T [576][96] bf16 bits; w3 [576][96] f32 -> w3T [96][576] f16.
// Values are small ints -> conversions exact.
// ---------------------------------------------------------------------------
__global__ void prep_kernel(const float* __restrict__ w1, const float* __restrict__ w3,
                            unsigned short* __restrict__ w1T, _Float16* __restrict__ w3T,
                            _Float16* __restrict__ x1h) {
  int i = blockIdx.x * blockDim.x + threadIdx.x;
  if (i >= CHID * CIN) return;
  if (i < CHID) x1h[(size_t)NS * CHID + i] = (_Float16)0.0f;  // zero row for invalid taps
  {
    int h = i / CIN, k = i % CIN;  // w1T[h][k] = w1[k][h]
    w1T[i] = (unsigned short)(__float_as_uint(w1[k * CHID + h]) >> 16);
  }
  {
    int o = i / CHID, k = i % CHID;  // w3T[o][k] = w3[k][o]
    w3T[i] = (_Float16)w3[k * COUT + o];
  }
}

// ---------------------------------------------------------------------------
// K1: expand GEMM  x1 = relu6(clamp(requant(feats@w1 + b1, s1)))  -> fp16 exact
// One wave per 16 sites; 36 h-tiles of 16; K=96 -> 3 MFMAs/tile.
// ---------------------------------------------------------------------------
__global__ __launch_bounds__(64) void expand_kernel(
    const float* __restrict__ feats, const float* __restrict__ b1,
    const float* __restrict__ s1, const unsigned short* __restrict__ w1T,
    _Float16* __restrict__ x1h) {
  const int lane = threadIdx.x;
  const int m = lane & 15, quad = lane >> 4;
  const int s0 = blockIdx.x * 16;

  short8 afrag[3];
  const float* arow = feats + (s0 + m) * CIN + quad * 8;
#pragma unroll
  for (int kc = 0; kc < 3; ++kc) {
    const float4 lo = *reinterpret_cast<const float4*>(arow + kc * 32);
    const float4 hi = *reinterpret_cast<const float4*>(arow + kc * 32 + 4);
    const float v[8] = {lo.x, lo.y, lo.z, lo.w, hi.x, hi.y, hi.z, hi.w};
#pragma unroll
    for (int j = 0; j < 8; ++j)
      afrag[kc][j] = (short)(__float_as_uint(v[j]) >> 16);  // exact: ints <=127
  }

  for (int ht = 0; ht < CHID / 16; ++ht) {
    const int h = ht * 16 + m;
    floatx4 acc = {0.f, 0.f, 0.f, 0.f};
#pragma unroll
    for (int kc = 0; kc < 3; ++kc) {
      const short8 bfrag =
          *reinterpret_cast<const short8*>(w1T + h * CIN + kc * 32 + quad * 8);
      acc = __builtin_amdgcn_mfma_f32_16x16x32_bf16(afrag[kc], bfrag, acc, 0, 0, 0);
    }
    const float scale = rintf(s1[h]) * (1.0f / 256.0f);
    const float bias = b1[h];
#pragma unroll
    for (int r = 0; r < 4; ++r) {
      const int site = s0 + quad * 4 + r;
      float v = (acc[r] + bias) * scale;
      v = fminf(fmaxf(v, 0.0f), 6.0f);
      x1h[(size_t)site * CHID + h] = (_Float16)v;
    }
  }
}

// ---------------------------------------------------------------------------
// K2 (fused): depthwise 3x3 -> LDS tile -> project MFMA -> residual -> out.
// Block = 576 threads (9 waves), SPB=48 sites.
// DW phase: thread = channel, branch-free gathers via zero-row redirect.
// Proj phase: 18 (3 site-tiles x 6 out-tiles) MFMA tiles, 2 per wave.
// ---------------------------------------------------------------------------
__global__ __launch_bounds__(576) void dwproj_kernel(
    const int* __restrict__ nbr, const float* __restrict__ w2,
    const float* __restrict__ b2, const float* __restrict__ s2,
    const _Float16* __restrict__ x1h, const _Float16* __restrict__ w3T,
    const float* __restrict__ feats, const float* __restrict__ b3,
    const float* __restrict__ s3, const float* __restrict__ s_main,
    const float* __restrict__ s_res, float* __restrict__ out) {
  __shared__ _Float16 x2t[SPB * LDH];
  const int t = threadIdx.x;
  const int s0 = blockIdx.x * SPB;

  // ---------------- DW phase ----------------
  {
    const int c = t;
    float w[9];
#pragma unroll
    for (int k = 0; k < 9; ++k) w[k] = w2[k * CHID + c];
    const float bias = b2[c];
    const float scale = rintf(s2[c]) * (1.0f / 256.0f);
#pragma unroll 4
    for (int n = 0; n < SPB; ++n) {
      const int site = s0 + n;
      const int sc = site < NS ? site : NS - 1;
      float acc = bias;
#pragma unroll
      for (int k = 0; k < 9; ++k) {
        const int idx = nbr[k * NS + sc];
        const int ix = idx < 0 ? NS : idx;  // invalid -> zero row (no branch)
        acc += (float)x1h[(size_t)ix * CHID + c] * w[k];
      }
      float v = acc * scale;
      v = fminf(fmaxf(v, 0.0f), 6.0f);
      x2t[n * LDH + c] = (_Float16)v;
    }
  }
  __syncthreads();

  // ---------------- Proj phase ----------------
  const int wave = t >> 6, lane = t & 63;
  const int m = lane & 15, quad = lane >> 4;
  const float rsm = rintf(s_main[0]) * 256.0f;
  const float rsr = rintf(s_res[0]) * 256.0f;

  for (int tile = wave; tile < (SPB / 16) * (COUT / 16); tile += 9) {
    const int tm = tile / (COUT / 16);   // site tile [0,3)
    const int ot = tile % (COUT / 16);   // out-ch tile [0,6)
    const int o = ot * 16 + m;
    floatx4 acc = {0.f, 0.f, 0.f, 0.f};
    const _Float16* brow = w3T + o * CHID + quad * 8;
    const _Float16* alds = x2t + (tm * 16 + m) * LDH + quad * 8;
#pragma unroll
    for (int kc = 0; kc < 18; ++kc) {
      const half8 a = *reinterpret_cast<const half8*>(alds + kc * 32);
      const half8 b = *reinterpret_cast<const half8*>(brow + kc * 32);
      acc = __builtin_amdgcn_mfma_f32_16x16x32_f16(a, b, acc, 0, 0, 0);
    }
    const float scale = rintf(s3[o]) * (1.0f / 256.0f);
    const float bias = b3[o];
#pragma unroll
    for (int r = 0; r < 4; ++r) {
      const int siteL = tm * 16 + quad * 4 + r;
      const int site = s0 + siteL;
      if (site < NS) {
        float v = (acc[r] + bias) * scale;
        v = fminf(fmaxf(v, -128.0f), 128.0f);
        out[site * COUT + o] = rsm * v + rsr * feats[site * COUT + o];
      }
    }
  }
}

// ---------------------------------------------------------------------------
extern "C" void kernel_launch(void* const* d_in, const int* in_sizes, int n_in,
                              void* d_out, int out_size, void* d_ws, size_t ws_size,
                              hipStream_t stream) {
  const float* feats  = (const float*)d_in[0];
  const int*   nbr    = (const int*)d_in[1];
  const float* w1     = (const float*)d_in[2];
  const float* b1     = (const float*)d_in[3];
  const float* w2     = (const float*)d_in[4];
  const float* b2     = (const float*)d_in[5];
  const float* w3     = (const float*)d_in[6];
  const float* b3     = (const float*)d_in[7];
  const float* s1     = (const float*)d_in[8];
  const float* s2     = (const float*)d_in[9];
  const float* s3     = (const float*)d_in[10];
  const float* s_main = (const float*)d_in[11];
  const float* s_res  = (const float*)d_in[12];
  float* out = (float*)d_out;

  char* ws = (char*)d_ws;
  // x1h: (NS+1) rows x 576 f16 = 115,201,152 B (last row = zeros for invalid taps)
  _Float16*       x1h = (_Float16*)ws;
  unsigned short* w1T = (unsigned short*)(ws + 115201152);  // 110,592 B (16B-aligned)
  _Float16*       w3T = (_Float16*)(ws + 115311744);        // 110,592 B

  prep_kernel<<<(CHID * CIN + 255) / 256, 256, 0, stream>>>(w1, w3, w1T, w3T, x1h);
  expand_kernel<<<NS / 16, 64, 0, stream>>>(feats, b1, s1, w1T, x1h);
  const int nblk = (NS + SPB - 1) / SPB;
  dwproj_kernel<<<nblk, 576, 0, stream>>>(nbr, w2, b2, s2, x1h, w3T,
                                          feats, b3, s3, s_main, s_res, out);
}

// Round 3
// 373.131 us; speedup vs baseline: 1.5788x; 1.0800x over previous
//
#include <hip/hip_runtime.h>
#include <hip/hip_bf16.h>
#include <hip/hip_fp16.h>

#define NS   100000
#define CIN  96
#define CHID 576
#define COUT 96
#define SPB  48              // sites per block in fused dw+proj
#define LDH  (CHID + 8)      // padded LDS row (halves)
#define CPT  4               // channels per thread in dw phase
#define NG   (CHID / CPT)    // 144 channel groups
#define NSLOT (576 / NG)     // 4 site slots
#define SPS  (SPB / NSLOT)   // 12 sites per slot

typedef float    floatx4 __attribute__((ext_vector_type(4)));
typedef int      intx4   __attribute__((ext_vector_type(4)));
typedef short    short8  __attribute__((ext_vector_type(8)));
typedef _Float16 half8   __attribute__((ext_vector_type(8)));
typedef _Float16 half4   __attribute__((ext_vector_type(4)));

// ---------------------------------------------------------------------------
// K0: transpose+convert weights; zero the dummy gather row x1h[NS].
// ---------------------------------------------------------------------------
__global__ void prep_kernel(const float* __restrict__ w1, const float* __restrict__ w3,
                            unsigned short* __restrict__ w1T, _Float16* __restrict__ w3T,
                            _Float16* __restrict__ x1h) {
  int i = blockIdx.x * blockDim.x + threadIdx.x;
  if (i >= CHID * CIN) return;
  if (i < CHID) x1h[(size_t)NS * CHID + i] = (_Float16)0.0f;
  {
    int h = i / CIN, k = i % CIN;  // w1T[h][k] = w1[k][h]
    w1T[i] = (unsigned short)(__float_as_uint(w1[k * CHID + h]) >> 16);
  }
  {
    int o = i / CHID, k = i % CHID;  // w3T[o][k] = w3[k][o]
    w3T[i] = (_Float16)w3[k * COUT + o];
  }
}

// ---------------------------------------------------------------------------
// K1: expand GEMM, operands swapped: D[h][site] = w1T-row · feats-row.
// Epilogue: lane holds 4 consecutive h for one site -> packed half4 store.
// ---------------------------------------------------------------------------
__global__ __launch_bounds__(64) void expand_kernel(
    const float* __restrict__ feats, const float* __restrict__ b1,
    const float* __restrict__ s1, const unsigned short* __restrict__ w1T,
    _Float16* __restrict__ x1h) {
  const int lane = threadIdx.x;
  const int m = lane & 15, quad = lane >> 4;
  const int s0 = blockIdx.x * 16;

  // B fragment: B[k][n=site] = feats[site][k]; lane n=m loads feats row s0+m.
  short8 bfrag[3];
  const float* frow = feats + (s0 + m) * CIN + quad * 8;
#pragma unroll
  for (int kc = 0; kc < 3; ++kc) {
    const float4 lo = *reinterpret_cast<const float4*>(frow + kc * 32);
    const float4 hi = *reinterpret_cast<const float4*>(frow + kc * 32 + 4);
    const float v[8] = {lo.x, lo.y, lo.z, lo.w, hi.x, hi.y, hi.z, hi.w};
#pragma unroll
    for (int j = 0; j < 8; ++j)
      bfrag[kc][j] = (short)(__float_as_uint(v[j]) >> 16);  // exact: ints <=127
  }

  const int hq = quad * 4;
#pragma unroll 4
  for (int ht = 0; ht < CHID / 16; ++ht) {
    floatx4 acc = {0.f, 0.f, 0.f, 0.f};
    const unsigned short* wrow = w1T + (ht * 16 + m) * CIN + quad * 8;
#pragma unroll
    for (int kc = 0; kc < 3; ++kc) {
      const short8 afrag = *reinterpret_cast<const short8*>(wrow + kc * 32);
      acc = __builtin_amdgcn_mfma_f32_16x16x32_bf16(afrag, bfrag[kc], acc, 0, 0, 0);
    }
    const floatx4 bv = *reinterpret_cast<const floatx4*>(b1 + ht * 16 + hq);
    const floatx4 sv = *reinterpret_cast<const floatx4*>(s1 + ht * 16 + hq);
    half4 r;
#pragma unroll
    for (int j = 0; j < 4; ++j) {
      float v = (acc[j] + bv[j]) * (rintf(sv[j]) * (1.0f / 256.0f));
      r[j] = (_Float16)fminf(fmaxf(v, 0.0f), 6.0f);
    }
    *reinterpret_cast<half4*>(x1h + (size_t)(s0 + m) * CHID + ht * 16 + hq) = r;
  }
}

// ---------------------------------------------------------------------------
// K2 (fused): dw 3x3 (4ch/thread, half4 gathers) -> LDS -> proj MFMA -> out.
// ---------------------------------------------------------------------------
__global__ __launch_bounds__(576) void dwproj_kernel(
    const int* __restrict__ nbr, const float* __restrict__ w2,
    const float* __restrict__ b2, const float* __restrict__ s2,
    const _Float16* __restrict__ x1h, const _Float16* __restrict__ w3T,
    const float* __restrict__ feats, const float* __restrict__ b3,
    const float* __restrict__ s3, const float* __restrict__ s_main,
    const float* __restrict__ s_res, float* __restrict__ out) {
  __shared__ _Float16 x2t[SPB * LDH];
  __shared__ int offt[SPB * 12];   // per-site tap offsets (elements), padded to 12
  const int t = threadIdx.x;
  const int s0 = blockIdx.x * SPB;

  // ---- preload neighbor offsets (zero-row redirect baked in) ----
  if (t < SPB * 9) {
    const int k = t / SPB, n = t - k * SPB;  // coalesced over n
    const int site = min(s0 + n, NS - 1);
    const int idx = nbr[k * NS + site];
    offt[n * 12 + k] = (idx < 0 ? NS : idx) * CHID;
  }
  __syncthreads();

  // ---------------- DW phase ----------------
  {
    const int g = t % NG;         // channel group -> channels c0..c0+3
    const int slot = t / NG;      // 0..3
    const int c0 = g * CPT;
    floatx4 w2f[9];
#pragma unroll
    for (int k = 0; k < 9; ++k)
      w2f[k] = *reinterpret_cast<const floatx4*>(w2 + k * CHID + c0);
    const floatx4 bv = *reinterpret_cast<const floatx4*>(b2 + c0);
    const floatx4 s2v = *reinterpret_cast<const floatx4*>(s2 + c0);
    floatx4 scv;
#pragma unroll
    for (int j = 0; j < 4; ++j) scv[j] = rintf(s2v[j]) * (1.0f / 256.0f);

#pragma unroll 2
    for (int i = 0; i < SPS; ++i) {
      const int n = slot * SPS + i;
      const intx4 oa = *reinterpret_cast<const intx4*>(offt + n * 12);
      const intx4 ob = *reinterpret_cast<const intx4*>(offt + n * 12 + 4);
      const int o8 = offt[n * 12 + 8];
      half4 v0 = *reinterpret_cast<const half4*>(x1h + (size_t)oa.x + c0);
      half4 v1 = *reinterpret_cast<const half4*>(x1h + (size_t)oa.y + c0);
      half4 v2 = *reinterpret_cast<const half4*>(x1h + (size_t)oa.z + c0);
      half4 v3 = *reinterpret_cast<const half4*>(x1h + (size_t)oa.w + c0);
      half4 v4 = *reinterpret_cast<const half4*>(x1h + (size_t)ob.x + c0);
      half4 v5 = *reinterpret_cast<const half4*>(x1h + (size_t)ob.y + c0);
      half4 v6 = *reinterpret_cast<const half4*>(x1h + (size_t)ob.z + c0);
      half4 v7 = *reinterpret_cast<const half4*>(x1h + (size_t)ob.w + c0);
      half4 v8 = *reinterpret_cast<const half4*>(x1h + (size_t)o8 + c0);
      floatx4 acc = bv;
      acc += __builtin_convertvector(v0, floatx4) * w2f[0];
      acc += __builtin_convertvector(v1, floatx4) * w2f[1];
      acc += __builtin_convertvector(v2, floatx4) * w2f[2];
      acc += __builtin_convertvector(v3, floatx4) * w2f[3];
      acc += __builtin_convertvector(v4, floatx4) * w2f[4];
      acc += __builtin_convertvector(v5, floatx4) * w2f[5];
      acc += __builtin_convertvector(v6, floatx4) * w2f[6];
      acc += __builtin_convertvector(v7, floatx4) * w2f[7];
      acc += __builtin_convertvector(v8, floatx4) * w2f[8];
      half4 r;
#pragma unroll
      for (int j = 0; j < 4; ++j) {
        float v = acc[j] * scv[j];
        r[j] = (_Float16)fminf(fmaxf(v, 0.0f), 6.0f);
      }
      *reinterpret_cast<half4*>(x2t + n * LDH + c0) = r;
    }
  }
  __syncthreads();

  // ---------------- Proj phase (operands swapped: D[o][site]) ----------------
  const int wave = t >> 6, lane = t & 63;
  const int m = lane & 15, quad = lane >> 4;
  const float rsm = rintf(s_main[0]) * 256.0f;
  const float rsr = rintf(s_res[0]) * 256.0f;

  for (int tile = wave; tile < (SPB / 16) * (COUT / 16); tile += 9) {
    const int tm = tile / (COUT / 16);
    const int ot = tile % (COUT / 16);
    floatx4 acc = {0.f, 0.f, 0.f, 0.f};
    const _Float16* arow = w3T + (ot * 16 + m) * CHID + quad * 8;  // A: w3 row (o)
    const _Float16* blds = x2t + (tm * 16 + m) * LDH + quad * 8;   // B: x2 row (site)
#pragma unroll
    for (int kc = 0; kc < 18; ++kc) {
      const half8 a = *reinterpret_cast<const half8*>(arow + kc * 32);
      const half8 b = *reinterpret_cast<const half8*>(blds + kc * 32);
      acc = __builtin_amdgcn_mfma_f32_16x16x32_f16(a, b, acc, 0, 0, 0);
    }
    const int site = s0 + tm * 16 + m;
    if (site < NS) {
      const int o0 = ot * 16 + quad * 4;
      const floatx4 b3v = *reinterpret_cast<const floatx4*>(b3 + o0);
      const floatx4 s3v = *reinterpret_cast<const floatx4*>(s3 + o0);
      const floatx4 fv =
          *reinterpret_cast<const floatx4*>(feats + (size_t)site * COUT + o0);
      floatx4 r;
#pragma unroll
      for (int j = 0; j < 4; ++j) {
        float v = (acc[j] + b3v[j]) * (rintf(s3v[j]) * (1.0f / 256.0f));
        v = fminf(fmaxf(v, -128.0f), 128.0f);
        r[j] = rsm * v + rsr * fv[j];
      }
      *reinterpret_cast<floatx4*>(out + (size_t)site * COUT + o0) = r;
    }
  }
}

// ---------------------------------------------------------------------------
extern "C" void kernel_launch(void* const* d_in, const int* in_sizes, int n_in,
                              void* d_out, int out_size, void* d_ws, size_t ws_size,
                              hipStream_t stream) {
  const float* feats  = (const float*)d_in[0];
  const int*   nbr    = (const int*)d_in[1];
  const float* w1     = (const float*)d_in[2];
  const float* b1     = (const float*)d_in[3];
  const float* w2     = (const float*)d_in[4];
  const float* b2     = (const float*)d_in[5];
  const float* w3     = (const float*)d_in[6];
  const float* b3     = (const float*)d_in[7];
  const float* s1     = (const float*)d_in[8];
  const float* s2     = (const float*)d_in[9];
  const float* s3     = (const float*)d_in[10];
  const float* s_main = (const float*)d_in[11];
  const float* s_res  = (const float*)d_in[12];
  float* out = (float*)d_out;

  char* ws = (char*)d_ws;
  _Float16*       x1h = (_Float16*)ws;                      // (NS+1)*576 f16
  unsigned short* w1T = (unsigned short*)(ws + 115201152);  // 110,592 B
  _Float16*       w3T = (_Float16*)(ws + 115311744);        // 110,592 B

  prep_kernel<<<(CHID * CIN + 255) / 256, 256, 0, stream>>>(w1, w3, w1T, w3T, x1h);
  expand_kernel<<<NS / 16, 64, 0, stream>>>(feats, b1, s1, w1T, x1h);
  const int nblk = (NS + SPB - 1) / SPB;
  dwproj_kernel<<<nblk, 576, 0, stream>>>(nbr, w2, b2, s2, x1h, w3T,
                                          feats, b3, s3, s_main, s_res, out);
}

// Round 4
// 332.845 us; speedup vs baseline: 1.7699x; 1.1210x over previous
//
#include <hip/hip_runtime.h>
#include <hip/hip_bf16.h>
#include <hip/hip_fp16.h>

#define NS   100000
#define CIN  96
#define CHID 576
#define COUT 96
#define SPB  48              // sites per block in fused dw+proj
#define LDH  (CHID + 8)      // padded LDS row (halves)
#define CPT  8               // channels per thread in dw phase
#define NG   (CHID / CPT)    // 72 channel groups
#define NSLOT (576 / NG)     // 8 site slots
#define SPS  (SPB / NSLOT)   // 6 sites per slot

typedef float    floatx4 __attribute__((ext_vector_type(4)));
typedef int      intx4   __attribute__((ext_vector_type(4)));
typedef short    short8  __attribute__((ext_vector_type(8)));
typedef _Float16 half8   __attribute__((ext_vector_type(8)));
typedef _Float16 half4   __attribute__((ext_vector_type(4)));

// ---------------------------------------------------------------------------
// K0: transpose+convert weights; zero dummy gather row x1h[NS]; w2 -> fp16.
// ---------------------------------------------------------------------------
__global__ void prep_kernel(const float* __restrict__ w1, const float* __restrict__ w3,
                            const float* __restrict__ w2,
                            unsigned short* __restrict__ w1T, _Float16* __restrict__ w3T,
                            _Float16* __restrict__ w2h, _Float16* __restrict__ x1h) {
  int i = blockIdx.x * blockDim.x + threadIdx.x;
  if (i >= CHID * CIN) return;
  if (i < CHID) x1h[(size_t)NS * CHID + i] = (_Float16)0.0f;
  if (i < 9 * CHID) w2h[i] = (_Float16)w2[i];  // ints <=127: exact
  {
    int h = i / CIN, k = i % CIN;  // w1T[h][k] = w1[k][h]
    w1T[i] = (unsigned short)(__float_as_uint(w1[k * CHID + h]) >> 16);
  }
  {
    int o = i / CHID, k = i % CHID;  // w3T[o][k] = w3[k][o]
    w3T[i] = (_Float16)w3[k * COUT + o];
  }
}

// ---------------------------------------------------------------------------
// K1: expand GEMM, swapped operands: D[h][site].  64 sites per wave (4 tiles)
// so each w1T A-frag feeds 4 MFMAs (4 independent chains).  1563 blocks.
// ---------------------------------------------------------------------------
__global__ __launch_bounds__(64) void expand_kernel(
    const float* __restrict__ feats, const float* __restrict__ b1,
    const float* __restrict__ s1, const unsigned short* __restrict__ w1T,
    _Float16* __restrict__ x1h) {
  const int lane = threadIdx.x;
  const int m = lane & 15, quad = lane >> 4;
  const int s0 = blockIdx.x * 64;

  // B fragments (feats) for 4 site tiles, kept in regs for the whole kernel.
  short8 bfrag[4][3];
#pragma unroll
  for (int u = 0; u < 4; ++u) {
    const int site = min(s0 + u * 16 + m, NS - 1);
    const float* frow = feats + (size_t)site * CIN + quad * 8;
#pragma unroll
    for (int kc = 0; kc < 3; ++kc) {
      const float4 lo = *reinterpret_cast<const float4*>(frow + kc * 32);
      const float4 hi = *reinterpret_cast<const float4*>(frow + kc * 32 + 4);
      const float v[8] = {lo.x, lo.y, lo.z, lo.w, hi.x, hi.y, hi.z, hi.w};
#pragma unroll
      for (int j = 0; j < 8; ++j)
        bfrag[u][kc][j] = (short)(__float_as_uint(v[j]) >> 16);  // exact
    }
  }

  const int hq = quad * 4;
#pragma unroll 2
  for (int ht = 0; ht < CHID / 16; ++ht) {
    const unsigned short* wrow = w1T + (ht * 16 + m) * CIN + quad * 8;
    short8 a[3];
#pragma unroll
    for (int kc = 0; kc < 3; ++kc)
      a[kc] = *reinterpret_cast<const short8*>(wrow + kc * 32);

    floatx4 acc[4] = {{0.f, 0.f, 0.f, 0.f}, {0.f, 0.f, 0.f, 0.f},
                      {0.f, 0.f, 0.f, 0.f}, {0.f, 0.f, 0.f, 0.f}};
#pragma unroll
    for (int kc = 0; kc < 3; ++kc)
#pragma unroll
      for (int u = 0; u < 4; ++u)
        acc[u] = __builtin_amdgcn_mfma_f32_16x16x32_bf16(a[kc], bfrag[u][kc], acc[u], 0, 0, 0);

    const floatx4 bv = *reinterpret_cast<const floatx4*>(b1 + ht * 16 + hq);
    const floatx4 sv = *reinterpret_cast<const floatx4*>(s1 + ht * 16 + hq);
    floatx4 sc;
#pragma unroll
    for (int j = 0; j < 4; ++j) sc[j] = rintf(sv[j]) * (1.0f / 256.0f);

#pragma unroll
    for (int u = 0; u < 4; ++u) {
      const int site = s0 + u * 16 + m;
      if (site < NS) {  // uniform per (block,u): NS % 16 == 0
        half4 r;
#pragma unroll
        for (int j = 0; j < 4; ++j) {
          float v = (acc[u][j] + bv[j]) * sc[j];
          r[j] = (_Float16)fminf(fmaxf(v, 0.0f), 6.0f);
        }
        *reinterpret_cast<half4*>(x1h + (size_t)site * CHID + ht * 16 + hq) = r;
      }
    }
  }
}

// ---------------------------------------------------------------------------
// K2 (fused): dw 3x3 (8ch/thread, half8 gathers) -> LDS -> proj MFMA -> out.
// ---------------------------------------------------------------------------
__global__ __launch_bounds__(576) void dwproj_kernel(
    const int* __restrict__ nbr, const _Float16* __restrict__ w2h,
    const float* __restrict__ b2, const float* __restrict__ s2,
    const _Float16* __restrict__ x1h, const _Float16* __restrict__ w3T,
    const float* __restrict__ feats, const float* __restrict__ b3,
    const float* __restrict__ s3, const float* __restrict__ s_main,
    const float* __restrict__ s_res, float* __restrict__ out) {
  __shared__ _Float16 x2t[SPB * LDH];
  __shared__ int offt[SPB * 12];   // per-site tap offsets (elements)
  const int t = threadIdx.x;
  const int s0 = blockIdx.x * SPB;

  if (t < SPB * 9) {
    const int k = t / SPB, n = t - k * SPB;
    const int site = min(s0 + n, NS - 1);
    const int idx = nbr[k * NS + site];
    offt[n * 12 + k] = (idx < 0 ? NS : idx) * CHID;  // zero-row redirect
  }
  __syncthreads();

  // ---------------- DW phase ----------------
  {
    const int g = t % NG;         // channel group -> channels c0..c0+7
    const int slot = t / NG;      // 0..7
    const int c0 = g * CPT;
    half8 wv[9];
#pragma unroll
    for (int k = 0; k < 9; ++k)
      wv[k] = *reinterpret_cast<const half8*>(w2h + k * CHID + c0);
    float bvv[8], scv[8];
    {
      const floatx4 b0 = *reinterpret_cast<const floatx4*>(b2 + c0);
      const floatx4 b1v = *reinterpret_cast<const floatx4*>(b2 + c0 + 4);
      const floatx4 sa = *reinterpret_cast<const floatx4*>(s2 + c0);
      const floatx4 sb = *reinterpret_cast<const floatx4*>(s2 + c0 + 4);
#pragma unroll
      for (int j = 0; j < 4; ++j) {
        bvv[j] = b0[j];     bvv[j + 4] = b1v[j];
        scv[j] = rintf(sa[j]) * (1.0f / 256.0f);
        scv[j + 4] = rintf(sb[j]) * (1.0f / 256.0f);
      }
    }
#pragma unroll 2
    for (int i = 0; i < SPS; ++i) {
      const int n = slot * SPS + i;
      const intx4 oa = *reinterpret_cast<const intx4*>(offt + n * 12);
      const intx4 ob = *reinterpret_cast<const intx4*>(offt + n * 12 + 4);
      const int o8 = offt[n * 12 + 8];
      half8 v0 = *reinterpret_cast<const half8*>(x1h + (size_t)oa.x + c0);
      half8 v1 = *reinterpret_cast<const half8*>(x1h + (size_t)oa.y + c0);
      half8 v2 = *reinterpret_cast<const half8*>(x1h + (size_t)oa.z + c0);
      half8 v3 = *reinterpret_cast<const half8*>(x1h + (size_t)oa.w + c0);
      half8 v4 = *reinterpret_cast<const half8*>(x1h + (size_t)ob.x + c0);
      half8 v5 = *reinterpret_cast<const half8*>(x1h + (size_t)ob.y + c0);
      half8 v6 = *reinterpret_cast<const half8*>(x1h + (size_t)ob.z + c0);
      half8 v7 = *reinterpret_cast<const half8*>(x1h + (size_t)ob.w + c0);
      half8 v8 = *reinterpret_cast<const half8*>(x1h + (size_t)o8 + c0);
      float acc[8];
#pragma unroll
      for (int j = 0; j < 8; ++j) acc[j] = bvv[j];
#pragma unroll
      for (int j = 0; j < 8; ++j) {
        acc[j] += (float)v0[j] * (float)wv[0][j];
        acc[j] += (float)v1[j] * (float)wv[1][j];
        acc[j] += (float)v2[j] * (float)wv[2][j];
        acc[j] += (float)v3[j] * (float)wv[3][j];
        acc[j] += (float)v4[j] * (float)wv[4][j];
        acc[j] += (float)v5[j] * (float)wv[5][j];
        acc[j] += (float)v6[j] * (float)wv[6][j];
        acc[j] += (float)v7[j] * (float)wv[7][j];
        acc[j] += (float)v8[j] * (float)wv[8][j];
      }
      half8 r;
#pragma unroll
      for (int j = 0; j < 8; ++j) {
        float v = acc[j] * scv[j];
        r[j] = (_Float16)fminf(fmaxf(v, 0.0f), 6.0f);
      }
      *reinterpret_cast<half8*>(x2t + n * LDH + c0) = r;
    }
  }
  __syncthreads();

  // ---------------- Proj phase (swapped: D[o][site]) ----------------
  const int wave = t >> 6, lane = t & 63;
  const int m = lane & 15, quad = lane >> 4;
  const float rsm = rintf(s_main[0]) * 256.0f;
  const float rsr = rintf(s_res[0]) * 256.0f;

  for (int tile = wave; tile < (SPB / 16) * (COUT / 16); tile += 9) {
    const int tm = tile / (COUT / 16);
    const int ot = tile % (COUT / 16);
    floatx4 acc = {0.f, 0.f, 0.f, 0.f};
    const _Float16* arow = w3T + (ot * 16 + m) * CHID + quad * 8;
    const _Float16* blds = x2t + (tm * 16 + m) * LDH + quad * 8;
#pragma unroll
    for (int kc = 0; kc < 18; ++kc) {
      const half8 a = *reinterpret_cast<const half8*>(arow + kc * 32);
      const half8 b = *reinterpret_cast<const half8*>(blds + kc * 32);
      acc = __builtin_amdgcn_mfma_f32_16x16x32_f16(a, b, acc, 0, 0, 0);
    }
    const int site = s0 + tm * 16 + m;
    if (site < NS) {
      const int o0 = ot * 16 + quad * 4;
      const floatx4 b3v = *reinterpret_cast<const floatx4*>(b3 + o0);
      const floatx4 s3v = *reinterpret_cast<const floatx4*>(s3 + o0);
      const floatx4 fv =
          *reinterpret_cast<const floatx4*>(feats + (size_t)site * COUT + o0);
      floatx4 r;
#pragma unroll
      for (int j = 0; j < 4; ++j) {
        float v = (acc[j] + b3v[j]) * (rintf(s3v[j]) * (1.0f / 256.0f));
        v = fminf(fmaxf(v, -128.0f), 128.0f);
        r[j] = rsm * v + rsr * fv[j];
      }
      *reinterpret_cast<floatx4*>(out + (size_t)site * COUT + o0) = r;
    }
  }
}

// ---------------------------------------------------------------------------
extern "C" void kernel_launch(void* const* d_in, const int* in_sizes, int n_in,
                              void* d_out, int out_size, void* d_ws, size_t ws_size,
                              hipStream_t stream) {
  const float* feats  = (const float*)d_in[0];
  const int*   nbr    = (const int*)d_in[1];
  const float* w1     = (const float*)d_in[2];
  const float* b1     = (const float*)d_in[3];
  const float* w2     = (const float*)d_in[4];
  const float* b2     = (const float*)d_in[5];
  const float* w3     = (const float*)d_in[6];
  const float* b3     = (const float*)d_in[7];
  const float* s1     = (const float*)d_in[8];
  const float* s2     = (const float*)d_in[9];
  const float* s3     = (const float*)d_in[10];
  const float* s_main = (const float*)d_in[11];
  const float* s_res  = (const float*)d_in[12];
  float* out = (float*)d_out;

  char* ws = (char*)d_ws;
  _Float16*       x1h = (_Float16*)ws;                      // (NS+1)*576 f16
  unsigned short* w1T = (unsigned short*)(ws + 115201152);  // 110,592 B
  _Float16*       w3T = (_Float16*)(ws + 115311744);        // 110,592 B
  _Float16*       w2h = (_Float16*)(ws + 115422336);        // 10,368 B

  prep_kernel<<<(CHID * CIN + 255) / 256, 256, 0, stream>>>(w1, w3, w2, w1T, w3T, w2h, x1h);
  expand_kernel<<<(NS + 63) / 64, 64, 0, stream>>>(feats, b1, s1, w1T, x1h);
  const int nblk = (NS + SPB - 1) / SPB;
  dwproj_kernel<<<nblk, 576, 0, stream>>>(nbr, w2h, b2, s2, x1h, w3T,
                                          feats, b3, s3, s_main, s_res, out);
}